// Round 3
// baseline (408.154 us; speedup 1.0000x reference)
//
#include <hip/hip_runtime.h>
#include <math.h>

// CRF forward-algorithm loss for B=32, S=512, L=64 labels.
// Strategy: per-batch block runs the recursion in *linear space* with
// per-step renormalization: q' = (q @ exp(E_s)) / max, Lacc += log(max).
// exp(E_s) is independent of the recursion -> loads are depth-4 pipelined.

constexpr int S_LEN = 512;
constexpr int NB    = 32;
constexpr int NL    = 64;
constexpr int LL    = NL * NL;   // 4096

__global__ __launch_bounds__(256) void crf_forward_kernel(
    const float* __restrict__ emits,   // [B, S, L*L] f32
    const int*   __restrict__ targets, // [B, S+1]
    const int*   __restrict__ mask,    // [B, S] (0/1)
    float*       __restrict__ ws)      // [0..31] logz, [32..63] score, [64..95] len
{
    const int b    = blockIdx.x;
    const int t    = threadIdx.x;
    const int wave = t >> 6;
    const int lane = t & 63;

    const float* __restrict__ eb = emits + (size_t)b * S_LEN * LL;

    __shared__ float part[2][4][64];
    __shared__ int   sh_len[4];
    __shared__ float sh_sc[4];

    // ---- sequence length = popcount(mask row) (mask is a contiguous prefix) ----
    {
        const int* mb = mask + b * S_LEN;
        int c = 0;
        for (int s = t; s < S_LEN; s += 256) c += (mb[s] != 0);
        #pragma unroll
        for (int off = 32; off > 0; off >>= 1) c += __shfl_down(c, off);
        if (lane == 0) sh_len[wave] = c;
    }
    __syncthreads();
    const int len = sh_len[0] + sh_len[1] + sh_len[2] + sh_len[3];

    // ---- gold-path score for this batch ----
    {
        const int* tb = targets + b * (S_LEN + 1);
        float sc = 0.f;
        for (int s = t; s < len; s += 256) {
            const int idx = tb[s] * NL + tb[s + 1];
            sc += eb[(size_t)s * LL + idx];
        }
        #pragma unroll
        for (int off = 32; off > 0; off >>= 1) sc += __shfl_down(sc, off);
        if (lane == 0) sh_sc[wave] = sc;
    }
    __syncthreads();

    // ---- init: alpha0[k] = emits[b, 0, BOS=0, k] ----
    const float a0 = eb[lane];
    float m0 = a0;
    #pragma unroll
    for (int off = 32; off > 0; off >>= 1) m0 = fmaxf(m0, __shfl_xor(m0, off));
    float q    = __expf(a0 - m0);  // lane l holds q[l]; identical across waves
    float Lacc = m0;

    // wave w owns source labels j in [16w, 16w+16); lane = destination k
    const int j0 = wave * 16;
    const float* __restrict__ ej = eb + j0 * NL + lane;

    // depth-4 software pipeline of the per-step 16 scalar loads (stride 256B,
    // fully coalesced across the wave). Static indexing only (no scratch).
    float buf[4][16];
    #pragma unroll
    for (int ph = 0; ph < 4; ++ph) {
        const int s = 1 + ph;
        if (s < len) {
            #pragma unroll
            for (int i = 0; i < 16; ++i)
                buf[ph][i] = ej[(size_t)s * LL + i * NL];
        }
    }

    for (int sb = 1; sb < len; sb += 4) {
        #pragma unroll
        for (int ph = 0; ph < 4; ++ph) {
            const int s = sb + ph;
            if (s >= len) break;  // uniform: len identical across the block

            float w[16];
            #pragma unroll
            for (int i = 0; i < 16; ++i) w[i] = __expf(buf[ph][i]);

            const int sp = s + 4;  // prefetch 4 steps ahead
            if (sp < len) {
                #pragma unroll
                for (int i = 0; i < 16; ++i)
                    buf[ph][i] = ej[(size_t)sp * LL + i * NL];
            }

            float acc = 0.f;
            #pragma unroll
            for (int i = 0; i < 16; ++i)
                acc = fmaf(__shfl(q, j0 + i), w[i], acc);

            part[s & 1][wave][lane] = acc;
            __syncthreads();
            const float sum = part[s & 1][0][lane] + part[s & 1][1][lane]
                            + part[s & 1][2][lane] + part[s & 1][3][lane];
            float mx = sum;
            #pragma unroll
            for (int off = 32; off > 0; off >>= 1) mx = fmaxf(mx, __shfl_xor(mx, off));
            q = sum * (1.0f / mx);
            Lacc += __logf(mx);
        }
    }

    // ---- log_z_b = Lacc + log(sum_k q[k]) ----
    float qs = q;
    #pragma unroll
    for (int off = 32; off > 0; off >>= 1) qs += __shfl_xor(qs, off);

    if (t == 0) {
        ws[b]      = Lacc + __logf(qs);
        ws[32 + b] = sh_sc[0] + sh_sc[1] + sh_sc[2] + sh_sc[3];
        ws[64 + b] = (float)len;
    }
}

__global__ void crf_final_kernel(const float* __restrict__ ws,
                                 float* __restrict__ out)
{
    const int l = threadIdx.x;  // 64 threads
    float lz = 0.f, sc = 0.f, tk = 0.f;
    if (l < NB) {
        lz = ws[l];
        sc = ws[32 + l];
        tk = ws[64 + l];
    }
    #pragma unroll
    for (int off = 32; off > 0; off >>= 1) {
        lz += __shfl_down(lz, off);
        sc += __shfl_down(sc, off);
        tk += __shfl_down(tk, off);
    }
    if (l == 0) out[0] = (lz - sc) / tk;
}

extern "C" void kernel_launch(void* const* d_in, const int* in_sizes, int n_in,
                              void* d_out, int out_size, void* d_ws, size_t ws_size,
                              hipStream_t stream) {
    const float* emits   = (const float*)d_in[0];
    const int*   targets = (const int*)d_in[1];
    const int*   mask    = (const int*)d_in[2];
    float*       out     = (float*)d_out;
    float*       ws      = (float*)d_ws;

    hipLaunchKernelGGL(crf_forward_kernel, dim3(NB), dim3(256), 0, stream,
                       emits, targets, mask, ws);
    hipLaunchKernelGGL(crf_final_kernel, dim3(1), dim3(64), 0, stream, ws, out);
}

// Round 4
// 377.875 us; speedup vs baseline: 1.0801x; 1.0801x over previous
//
#include <hip/hip_runtime.h>
#include <math.h>

// CRF forward loss, B=32, S=512, L=64.
// Linear-space recursion q' = (q @ exp(E_s)) with renorm-by-max every 4 steps.
// Per-batch block, 4 waves split source labels j (16 each), lane = dest label k.
// KEY: raw s_barrier + lgkmcnt-only wait keeps the 8-step global prefetch in
// flight across the per-step barrier (__syncthreads would drain vmcnt(0)).

constexpr int S_LEN = 512;
constexpr int NB    = 32;
constexpr int NL    = 64;
constexpr int LL    = NL * NL;   // 4096

__device__ __forceinline__ float bcast_lane(float v, int sl) {
    return __int_as_float(__builtin_amdgcn_readlane(__float_as_int(v), sl));
}

// One recursion step. PH is a compile-time phase 0..7; WC = current step's
// exp'd weights, WN = next step's (produced here, one step early so the
// trans-pipe latency is off the q-critical-path).
#define STEP(PH, WC, WN)                                                      \
    do {                                                                      \
        const int s = sb + (PH);                                              \
        if (s < len) {                                                        \
            const int sp = s + 8;                                             \
            if (sp < len) {                                                   \
                _Pragma("unroll")                                             \
                for (int i = 0; i < 16; ++i)                                  \
                    buf[PH][i] = ej[(size_t)sp * LL + i * NL];                \
            }                                                                 \
            if (s + 1 < len) {                                                \
                _Pragma("unroll")                                             \
                for (int i = 0; i < 16; ++i)                                  \
                    WN[i] = __expf(buf[((PH) + 1) & 7][i]);                   \
            }                                                                 \
            float a0_ = 0.f, a1_ = 0.f, a2_ = 0.f, a3_ = 0.f;                 \
            _Pragma("unroll")                                                 \
            for (int i = 0; i < 16; i += 4) {                                 \
                a0_ = fmaf(bcast_lane(q, jbase + i + 0), WC[i + 0], a0_);     \
                a1_ = fmaf(bcast_lane(q, jbase + i + 1), WC[i + 1], a1_);     \
                a2_ = fmaf(bcast_lane(q, jbase + i + 2), WC[i + 2], a2_);     \
                a3_ = fmaf(bcast_lane(q, jbase + i + 3), WC[i + 3], a3_);     \
            }                                                                 \
            part[s & 1][wave][lane] = (a0_ + a1_) + (a2_ + a3_);              \
            asm volatile("s_waitcnt lgkmcnt(0)" ::: "memory");                \
            __builtin_amdgcn_s_barrier();                                     \
            asm volatile("" ::: "memory");                                    \
            float sum = part[s & 1][0][lane] + part[s & 1][1][lane]           \
                      + part[s & 1][2][lane] + part[s & 1][3][lane];          \
            if ((((PH) & 3) == 3) || s == len - 1) {                          \
                float mx = sum;                                               \
                _Pragma("unroll")                                             \
                for (int off = 32; off; off >>= 1)                            \
                    mx = fmaxf(mx, __shfl_xor(mx, off));                      \
                q = sum * __builtin_amdgcn_rcpf(mx);                          \
                Lacc += __logf(mx);                                           \
            } else {                                                          \
                q = sum;                                                      \
            }                                                                 \
        }                                                                     \
    } while (0)

__global__ __launch_bounds__(256) void crf_forward_kernel(
    const float* __restrict__ emits,   // [B, S, L*L] f32
    const int*   __restrict__ targets, // [B, S+1]
    const int*   __restrict__ mask,    // [B, S] (0/1)
    float*       __restrict__ ws)      // [0..31] logz, [32..63] score, [64..95] len
{
    const int b    = blockIdx.x;
    const int t    = threadIdx.x;
    const int wave = t >> 6;
    const int lane = t & 63;

    const float* __restrict__ eb = emits + (size_t)b * S_LEN * LL;

    __shared__ float part[2][4][64];
    __shared__ int   sh_len[4];
    __shared__ float sh_sc[4];

    // ---- sequence length (mask is a contiguous prefix) ----
    {
        const int* mb = mask + b * S_LEN;
        int c = 0;
        for (int s = t; s < S_LEN; s += 256) c += (mb[s] != 0);
        #pragma unroll
        for (int off = 32; off; off >>= 1) c += __shfl_down(c, off);
        if (lane == 0) sh_len[wave] = c;
    }
    __syncthreads();
    const int len = sh_len[0] + sh_len[1] + sh_len[2] + sh_len[3];

    // ---- gold-path score ----
    {
        const int* tb = targets + b * (S_LEN + 1);
        float sc = 0.f;
        for (int s = t; s < len; s += 256) {
            const int idx = tb[s] * NL + tb[s + 1];
            sc += eb[(size_t)s * LL + idx];
        }
        #pragma unroll
        for (int off = 32; off; off >>= 1) sc += __shfl_down(sc, off);
        if (lane == 0) sh_sc[wave] = sc;
    }
    __syncthreads();

    // ---- init: alpha0[k] = emits[b,0,BOS=0,k], renormalized ----
    const float a0 = eb[lane];
    float m0 = a0;
    #pragma unroll
    for (int off = 32; off; off >>= 1) m0 = fmaxf(m0, __shfl_xor(m0, off));
    float q    = __expf(a0 - m0);   // lane k holds q[k]; replicated per wave
    float Lacc = m0;

    const int jbase = __builtin_amdgcn_readfirstlane(wave) * 16;  // SGPR
    const float* __restrict__ ej = eb + jbase * NL + lane;

    // ---- 8-deep software pipeline of raw emit loads ----
    float buf[8][16];
    #pragma unroll
    for (int ph = 0; ph < 8; ++ph) {
        const int s = 1 + ph;
        if (s < len) {
            #pragma unroll
            for (int i = 0; i < 16; ++i)
                buf[ph][i] = ej[(size_t)s * LL + i * NL];
        }
    }
    float wA[16], wB[16];
    #pragma unroll
    for (int i = 0; i < 16; ++i) wA[i] = __expf(buf[0][i]);  // step 1 (len>=2)

    for (int sb = 1; sb < len; sb += 8) {
        STEP(0, wA, wB);
        STEP(1, wB, wA);
        STEP(2, wA, wB);
        STEP(3, wB, wA);
        STEP(4, wA, wB);
        STEP(5, wB, wA);
        STEP(6, wA, wB);
        STEP(7, wB, wA);
    }

    // ---- log_z_b = Lacc + log(sum_k q[k]) ----
    float qs = q;
    #pragma unroll
    for (int off = 32; off; off >>= 1) qs += __shfl_xor(qs, off);

    if (t == 0) {
        ws[b]      = Lacc + __logf(qs);
        ws[32 + b] = sh_sc[0] + sh_sc[1] + sh_sc[2] + sh_sc[3];
        ws[64 + b] = (float)len;
    }
}

__global__ void crf_final_kernel(const float* __restrict__ ws,
                                 float* __restrict__ out)
{
    const int l = threadIdx.x;  // 64 threads
    float lz = 0.f, sc = 0.f, tk = 0.f;
    if (l < NB) {
        lz = ws[l];
        sc = ws[32 + l];
        tk = ws[64 + l];
    }
    #pragma unroll
    for (int off = 32; off; off >>= 1) {
        lz += __shfl_down(lz, off);
        sc += __shfl_down(sc, off);
        tk += __shfl_down(tk, off);
    }
    if (l == 0) out[0] = (lz - sc) / tk;
}

extern "C" void kernel_launch(void* const* d_in, const int* in_sizes, int n_in,
                              void* d_out, int out_size, void* d_ws, size_t ws_size,
                              hipStream_t stream) {
    const float* emits   = (const float*)d_in[0];
    const int*   targets = (const int*)d_in[1];
    const int*   mask    = (const int*)d_in[2];
    float*       out     = (float*)d_out;
    float*       ws      = (float*)d_ws;

    hipLaunchKernelGGL(crf_forward_kernel, dim3(NB), dim3(256), 0, stream,
                       emits, targets, mask, ws);
    hipLaunchKernelGGL(crf_final_kernel, dim3(1), dim3(64), 0, stream, ws, out);
}

// Round 5
// 282.214 us; speedup vs baseline: 1.4463x; 1.3390x over previous
//
#include <hip/hip_runtime.h>
#include <math.h>

// CRF forward loss, B=32, S=512, L=64.
// Producer/consumer MFMA design:
//  - consumer wave 0: recursion q'^T = (W^T q^T) via 16x16x16 f16 MFMA;
//    D-frag layout makes B-frag rebuild lane-local (no cross-lane ops).
//  - producer waves 1-4: w = exp(e - 6*ln2) as f16 into a 16-step LDS ring,
//    tile loads double-buffered in registers, barrier once per 4 steps.
//  - renorm every 2 steps via readlane-max + exponent trick (f32 accs).

constexpr int S_LEN = 512;
constexpr int NB    = 32;
constexpr int NL    = 64;
constexpr int LL    = NL * NL;   // 4096
constexpr int RING  = 16;

#define LN2F 0.69314718055994531f
#define PREF 4.15888308335967186f  /* 6*ln2: w = exp(e)*2^-6 */

typedef _Float16 h4 __attribute__((ext_vector_type(4)));
typedef float    f4 __attribute__((ext_vector_type(4)));

union U4 { unsigned u[2]; h4 v; };

__device__ __forceinline__ float bl(float v, int sl) {
    return __int_as_float(__builtin_amdgcn_readlane(__float_as_int(v), sl));
}
__device__ __forceinline__ unsigned pk2(float a, float b) {
    auto r = __builtin_amdgcn_cvt_pkrtz(a, b);
    return __builtin_bit_cast(unsigned, r);
}

__global__ __launch_bounds__(320, 1) void crf_fwd(
    const float* __restrict__ emits,   // [B,S,4096] f32
    const int*   __restrict__ targets, // [B,S+1]
    const int*   __restrict__ mask,    // [B,S]
    float*       __restrict__ ws)
{
    const int b    = blockIdx.x;
    const int t    = threadIdx.x;
    const int wave = t >> 6;
    const int lane = t & 63;
    const float* __restrict__ eb = emits + (size_t)b * S_LEN * LL;

    // ring: slot s&15; element (jq,k,u) = w[4jq+u][k] f16, k XOR-swizzled
    __shared__ _Float16 W[RING][1024][4];   // 128 KB

    // ---- len (each wave independently; mask is contiguous prefix) ----
    int len;
    {
        const int* mb = mask + b * S_LEN;
        int c = 0;
        #pragma unroll
        for (int i = 0; i < 8; ++i) c += (mb[i * 64 + lane] != 0);
        #pragma unroll
        for (int off = 32; off; off >>= 1) c += __shfl_xor(c, off);
        len = c;
    }
    const int P = (len + 2) >> 2;   // ceil((len-1)/4) periods

    if (wave >= 1) {
        // ================= PRODUCERS (waves 1..4) =================
        const int pw = wave - 1;          // 0..3
        // gold-path partial score (1/4 of steps each)
        {
            const int* tb = targets + b * (S_LEN + 1);
            float sc = 0.f;
            for (int i = pw * 64 + lane; i < len; i += 256)
                sc += eb[(size_t)i * LL + tb[i] * NL + tb[i + 1]];
            #pragma unroll
            for (int off = 32; off; off >>= 1) sc += __shfl_xor(sc, off);
            if (lane == 0) ws[96 + 4 * b + pw] = sc;
        }
        const int jo = lane >> 4;         // j offset within quad
        const int kb = 4 * (lane & 15);   // k base
        f4 tb0[4][4], tb1[4][4];          // [stepq][jj]

#define LOADT(TB, BS)                                                        \
        do { _Pragma("unroll")                                               \
            for (int q = 0; q < 4; ++q) {                                    \
                const int s = (BS) + q;                                      \
                if (s < len) { _Pragma("unroll")                             \
                    for (int jj = 0; jj < 4; ++jj) {                         \
                        const int jq = 4 * pw + jj;                          \
                        TB[q][jj] = *reinterpret_cast<const f4*>(            \
                            eb + (size_t)s * LL + (4 * jq + jo) * NL + kb);  \
                    } } } } while (0)

#define PROCT(TB, BS)                                                        \
        do { _Pragma("unroll")                                               \
            for (int q = 0; q < 4; ++q) {                                    \
                const int s = (BS) + q;                                      \
                if (s < len) { const int slot = s & (RING - 1);              \
                    _Pragma("unroll")                                        \
                    for (int jj = 0; jj < 4; ++jj) {                         \
                        const int jq = 4 * pw + jj;                          \
                        const int kx = (jq & 3) << 2;                        \
                        _Pragma("unroll")                                    \
                        for (int kk = 0; kk < 4; ++kk) {                     \
                            float wv = __expf(TB[q][jj][kk] - PREF);         \
                            W[slot][jq * 64 + ((kb + kk) ^ kx)][jo] =        \
                                (_Float16)wv;                                \
                        } } } } } while (0)

        LOADT(tb0, 1);  PROCT(tb0, 1);    // batch 0: steps 1..4
        LOADT(tb1, 5);  PROCT(tb1, 5);    // batch 1: steps 5..8
        LOADT(tb0, 9);                    // issue batch 2 loads
        asm volatile("s_waitcnt lgkmcnt(0)" ::: "memory");
        __builtin_amdgcn_s_barrier();     // priming barrier
        for (int p = 0; p < P; ++p) {
            if (p & 1) { PROCT(tb1, 4 * p + 9); LOADT(tb0, 4 * p + 13); }
            else       { PROCT(tb0, 4 * p + 9); LOADT(tb1, 4 * p + 13); }
            asm volatile("s_waitcnt lgkmcnt(0)" ::: "memory");
            __builtin_amdgcn_s_barrier();
        }
    } else {
        // ================= CONSUMER (wave 0) =================
        const int mh = lane >> 4;               // 0..3
        const bool on = (lane & 15) == 0;       // column-0 lanes
        const f4 FZ = {0.f, 0.f, 0.f, 0.f};
        const h4 HZ = {(_Float16)0, (_Float16)0, (_Float16)0, (_Float16)0};

        // ---- init from BOS row: alpha0[k] = eb[k] ----
        float xv[4][4];
        #pragma unroll
        for (int r = 0; r < 4; ++r)
            #pragma unroll
            for (int u = 0; u < 4; ++u)
                xv[r][u] = eb[16 * r + 4 * mh + u];
        float lm = xv[0][0];
        #pragma unroll
        for (int r = 0; r < 4; ++r)
            #pragma unroll
            for (int u = 0; u < 4; ++u) lm = fmaxf(lm, xv[r][u]);
        const float m0 = fmaxf(fmaxf(bl(lm, 0), bl(lm, 16)),
                               fmaxf(bl(lm, 32), bl(lm, 48)));
        float Lacc = m0;
        h4 B[4];
        #pragma unroll
        for (int r = 0; r < 4; ++r) {
            U4 x;
            x.u[0] = pk2(__expf(xv[r][0] - m0), __expf(xv[r][1] - m0));
            x.u[1] = pk2(__expf(xv[r][2] - m0), __expf(xv[r][3] - m0));
            B[r] = on ? x.v : HZ;
        }

        f4 acc0 = FZ, acc1 = FZ, acc2 = FZ, acc3 = FZ;
        h4 Af0[4][4], Af1[4][4];   // [r][c], double-buffered

#define LOADA(AF, S)                                                         \
        do { if ((S) < len) { const int slot = (S) & (RING - 1);             \
            const int kx = mh << 2;                                          \
            _Pragma("unroll") for (int r = 0; r < 4; ++r) {                  \
                _Pragma("unroll") for (int cc = 0; cc < 4; ++cc) {           \
                    AF[r][cc] = *reinterpret_cast<const h4*>(                \
                        &W[slot][(4 * r + mh) * 64 +                         \
                                 ((16 * cc + (lane & 15)) ^ kx)][0]);        \
                } } } } while (0)

#define DOSTEP(AF, S)                                                        \
        do { if ((S) < len) {                                                \
            acc0 = FZ; acc1 = FZ; acc2 = FZ; acc3 = FZ;                      \
            _Pragma("unroll") for (int r = 0; r < 4; ++r) {                  \
                acc0 = __builtin_amdgcn_mfma_f32_16x16x16f16(                \
                    AF[r][0], B[r], acc0, 0, 0, 0);                          \
                acc1 = __builtin_amdgcn_mfma_f32_16x16x16f16(                \
                    AF[r][1], B[r], acc1, 0, 0, 0);                          \
                acc2 = __builtin_amdgcn_mfma_f32_16x16x16f16(                \
                    AF[r][2], B[r], acc2, 0, 0, 0);                          \
                acc3 = __builtin_amdgcn_mfma_f32_16x16x16f16(                \
                    AF[r][3], B[r], acc3, 0, 0, 0);                          \
            }                                                                \
            Lacc += PREF;                                                    \
            if ((S) != len - 1) {                                            \
                float scale = 1.0f;                                          \
                if (((S) & 1) == 0) {                                        \
                    float mm = acc0[0];                                      \
                    _Pragma("unroll") for (int u = 0; u < 4; ++u)            \
                        mm = fmaxf(mm, fmaxf(fmaxf(acc0[u], acc1[u]),        \
                                             fmaxf(acc2[u], acc3[u])));      \
                    const float gm = fmaxf(fmaxf(bl(mm, 0), bl(mm, 16)),     \
                                           fmaxf(bl(mm, 32), bl(mm, 48)));   \
                    const int E = (__float_as_int(gm) >> 23) & 0xFF;         \
                    scale = __int_as_float((254 - E) << 23);                 \
                    Lacc += (float)(E - 127) * LN2F;                         \
                }                                                            \
                U4 y0, y1, y2, y3;                                           \
                y0.u[0] = pk2(acc0[0] * scale, acc0[1] * scale);             \
                y0.u[1] = pk2(acc0[2] * scale, acc0[3] * scale);             \
                y1.u[0] = pk2(acc1[0] * scale, acc1[1] * scale);             \
                y1.u[1] = pk2(acc1[2] * scale, acc1[3] * scale);             \
                y2.u[0] = pk2(acc2[0] * scale, acc2[1] * scale);             \
                y2.u[1] = pk2(acc2[2] * scale, acc2[3] * scale);             \
                y3.u[0] = pk2(acc3[0] * scale, acc3[1] * scale);             \
                y3.u[1] = pk2(acc3[2] * scale, acc3[3] * scale);             \
                B[0] = on ? y0.v : HZ;  B[1] = on ? y1.v : HZ;               \
                B[2] = on ? y2.v : HZ;  B[3] = on ? y3.v : HZ;               \
            } } } while (0)

        __builtin_amdgcn_s_barrier();     // priming barrier
        LOADA(Af0, 1);
        for (int p = 0; p < P; ++p) {
            const int s0 = 4 * p + 1;
            LOADA(Af1, s0 + 1); DOSTEP(Af0, s0);
            LOADA(Af0, s0 + 2); DOSTEP(Af1, s0 + 1);
            LOADA(Af1, s0 + 3); DOSTEP(Af0, s0 + 2);
            LOADA(Af0, s0 + 4); DOSTEP(Af1, s0 + 3);
            asm volatile("s_waitcnt lgkmcnt(0)" ::: "memory");
            __builtin_amdgcn_s_barrier();
        }

        // ---- log_z_b = Lacc + log(sum of final accs) ----
        float Sl = 0.f;
        #pragma unroll
        for (int u = 0; u < 4; ++u)
            Sl += (acc0[u] + acc1[u]) + (acc2[u] + acc3[u]);
        const float tot = (bl(Sl, 0) + bl(Sl, 16)) + (bl(Sl, 32) + bl(Sl, 48));
        if (lane == 0) {
            ws[b]      = Lacc + __logf(tot);
            ws[64 + b] = (float)len;
        }
    }
}

__global__ void crf_final(const float* __restrict__ ws, float* __restrict__ out)
{
    const int l = threadIdx.x;  // 64 threads
    float lz = 0.f, tk = 0.f;
    if (l < NB) { lz = ws[l]; tk = ws[64 + l]; }
    float sc = ws[96 + l] + ws[160 + l];
    #pragma unroll
    for (int off = 32; off; off >>= 1) {
        lz += __shfl_down(lz, off);
        sc += __shfl_down(sc, off);
        tk += __shfl_down(tk, off);
    }
    if (l == 0) out[0] = (lz - sc) / tk;
}

extern "C" void kernel_launch(void* const* d_in, const int* in_sizes, int n_in,
                              void* d_out, int out_size, void* d_ws, size_t ws_size,
                              hipStream_t stream) {
    const float* emits   = (const float*)d_in[0];
    const int*   targets = (const int*)d_in[1];
    const int*   mask    = (const int*)d_in[2];
    float*       out     = (float*)d_out;
    float*       ws      = (float*)d_ws;

    hipLaunchKernelGGL(crf_fwd, dim3(NB), dim3(320), 0, stream,
                       emits, targets, mask, ws);
    hipLaunchKernelGGL(crf_final, dim3(1), dim3(64), 0, stream, ws, out);
}

// Round 6
// 107.524 us; speedup vs baseline: 3.7959x; 2.6247x over previous
//
#include <hip/hip_runtime.h>
#include <math.h>

// CRF forward loss, B=32, S=512, L=64 — chunked-matrix-product formulation.
// alpha_final^T = M^T_{len-1} ... M^T_1 alpha0^T  with M_s = exp(E_s)*2^-9.
// Phase 1: 512 single-wave blocks, each computes a 32-matrix chunk product
//          in f16 MFMA with renorm-by-max every 2 steps (no LDS, no barriers).
// Phase 2: 32 single-wave blocks fold the 16 chunk matrices into alpha0 as
//          mat-vecs (lane-local D->B rebuild, col-0 trick from round 5).
// Phase 3: final reduction to the scalar loss.

constexpr int S_LEN   = 512;
constexpr int NB      = 32;
constexpr int NL      = 64;
constexpr int LL      = 4096;
constexpr int CL      = 32;   // matrices per chunk
constexpr int NCH     = 16;   // chunks per batch
constexpr int NCHUNKS = NB * NCH;  // 512

#define LN2F  0.69314718055994531f
#define PREF  6.2383246250395078f   /* 9*ln2 : M = exp(E)*2^-9 */
#define LOG2E 1.4426950408889634f

typedef _Float16 h4 __attribute__((ext_vector_type(4)));
typedef float    f4 __attribute__((ext_vector_type(4)));
union U4 { unsigned u[2]; h4 v; };

__device__ __forceinline__ float bl(float v, int sl) {
  return __int_as_float(__builtin_amdgcn_readlane(__float_as_int(v), sl));
}
__device__ __forceinline__ unsigned pk2(float a, float b) {
  auto r = __builtin_amdgcn_cvt_pkrtz(a, b);
  return __builtin_bit_cast(unsigned, r);
}
__device__ __forceinline__ float expw(float x) {  // exp(x) * 2^-9
  return exp2f(__builtin_fmaf(x, LOG2E, -9.0f));
}

// ---------------- Phase 1: chunk products ----------------
__global__ __launch_bounds__(64) void crf_chunk(
    const float* __restrict__ emits,
    const int*   __restrict__ targets,
    const int*   __restrict__ mask,
    _Float16*    __restrict__ matP,   // [512][4096] f16
    float*       __restrict__ wsf)    // [0,512): Lacc ; [512,1024): gold
{
  const int ci   = blockIdx.x;
  const int b    = ci >> 4;
  const int cc   = ci & 15;
  const int lane = threadIdx.x;
  const int c    = lane & 15;
  const int h    = lane >> 4;
  const float* __restrict__ eb = emits + (size_t)b * (S_LEN * LL);

  // sequence length (mask is a contiguous prefix)
  int len;
  {
    const int* mb = mask + b * S_LEN;
    int cnt = 0;
    #pragma unroll
    for (int i = 0; i < 8; ++i) cnt += (mb[i * 64 + lane] != 0);
    #pragma unroll
    for (int off = 32; off; off >>= 1) cnt += __shfl_xor(cnt, off);
    len = cnt;
  }

  // gold partial: emissions s in [32cc, 32cc+32) ∩ [0,len)
  {
    float g = 0.f;
    const int s = 32 * cc + (lane & 31);
    if (lane < 32 && s < len) {
      const int* tb = targets + b * (S_LEN + 1);
      g = eb[(size_t)s * LL + tb[s] * NL + tb[s + 1]];
    }
    #pragma unroll
    for (int off = 32; off; off >>= 1) g += __shfl_xor(g, off);
    if (lane == 0) wsf[512 + ci] = g;
  }

  const int s0 = 32 * cc + 1;          // first transition matrix of the chunk
  const int n  = min(len - s0, CL);    // matrices in this chunk
  if (n < 1) return;

  float Lacc = PREF;

  // prefetch raw E for matrix j=1 (always in-bounds memory)
  float LB[4][4][4];  // [I][K][i]
  {
    const float* ep = eb + (size_t)(s0 + 1) * LL;
    #pragma unroll
    for (int I = 0; I < 4; ++I)
      #pragma unroll
      for (int K = 0; K < 4; ++K)
        #pragma unroll
        for (int i = 0; i < 4; ++i)
          LB[I][K][i] = ep[(16 * K + 4 * h + i) * 64 + 16 * I + c];
  }

  // B-frags init from matrix j=0:  P^T = M^T_{s0}
  // B tile(K,J)[i] = M[16J+c][16K+4h+i] -> contiguous f4 load
  h4 bf[4][4];
  {
    const float* ep = eb + (size_t)s0 * LL;
    #pragma unroll
    for (int K = 0; K < 4; ++K)
      #pragma unroll
      for (int J = 0; J < 4; ++J) {
        f4 la = *reinterpret_cast<const f4*>(ep + (16 * J + c) * 64 + 16 * K + 4 * h);
        U4 x;
        x.u[0] = pk2(expw(la[0]), expw(la[1]));
        x.u[1] = pk2(expw(la[2]), expw(la[3]));
        bf[K][J] = x.v;
      }
  }

  for (int j = 1; j < n; ++j) {
    // A-frags for matrix j: A tile(I,K)[i] = M[16K+4h+i][16I+c]
    h4 af[4][4];
    #pragma unroll
    for (int I = 0; I < 4; ++I)
      #pragma unroll
      for (int K = 0; K < 4; ++K) {
        U4 x;
        x.u[0] = pk2(expw(LB[I][K][0]), expw(LB[I][K][1]));
        x.u[1] = pk2(expw(LB[I][K][2]), expw(LB[I][K][3]));
        af[I][K] = x.v;
      }
    // prefetch matrix j+1
    if (j + 1 < n) {
      const float* ep = eb + (size_t)(s0 + j + 1) * LL;
      #pragma unroll
      for (int I = 0; I < 4; ++I)
        #pragma unroll
        for (int K = 0; K < 4; ++K)
          #pragma unroll
          for (int i = 0; i < 4; ++i)
            LB[I][K][i] = ep[(16 * K + 4 * h + i) * 64 + 16 * I + c];
    }
    // D = M^T_j x P^T   (16 tiles, 4-deep K chains)
    f4 dd[4][4];
    #pragma unroll
    for (int I = 0; I < 4; ++I)
      #pragma unroll
      for (int J = 0; J < 4; ++J) {
        f4 d = {0.f, 0.f, 0.f, 0.f};
        #pragma unroll
        for (int K = 0; K < 4; ++K)
          d = __builtin_amdgcn_mfma_f32_16x16x16f16(af[I][K], bf[K][J], d, 0, 0, 0);
        dd[I][J] = d;
      }
    Lacc += PREF;
    // renorm-by-max (exponent trick) every even j and at the final step
    float scale = 1.0f;
    if (((j & 1) == 0) || (j == n - 1)) {
      float mm = dd[0][0][0];
      #pragma unroll
      for (int I = 0; I < 4; ++I)
        #pragma unroll
        for (int J = 0; J < 4; ++J)
          #pragma unroll
          for (int u = 0; u < 4; ++u) mm = fmaxf(mm, dd[I][J][u]);
      #pragma unroll
      for (int off = 32; off; off >>= 1) mm = fmaxf(mm, __shfl_xor(mm, off));
      const int E = (__float_as_int(mm) >> 23) & 0xFF;
      scale = __int_as_float((254 - E) << 23);   // 2^(127-E): max -> [1,2)
      Lacc += (float)(E - 127) * LN2F;
    }
    // lane-local D -> B rebuild (B tile(K=I,J)[i] = D tile(I,J) reg i)
    #pragma unroll
    for (int I = 0; I < 4; ++I)
      #pragma unroll
      for (int J = 0; J < 4; ++J) {
        U4 y;
        y.u[0] = pk2(dd[I][J][0] * scale, dd[I][J][1] * scale);
        y.u[1] = pk2(dd[I][J][2] * scale, dd[I][J][3] * scale);
        bf[I][J] = y.v;
      }
  }

  // store P^T in phase-2 A-frag-friendly layout: [tile I*4+J][i][lane]
  {
    _Float16* mp = matP + (size_t)ci * 4096;
    #pragma unroll
    for (int I = 0; I < 4; ++I)
      #pragma unroll
      for (int J = 0; J < 4; ++J)
        #pragma unroll
        for (int i = 0; i < 4; ++i)
          mp[(I * 4 + J) * 256 + i * 64 + lane] = bf[I][J][i];
  }
  if (lane == 0) wsf[ci] = Lacc;
}

// ---------------- Phase 2: fold chunks into alpha0 ----------------
__global__ __launch_bounds__(64) void crf_fold(
    const float* __restrict__ emits,
    const int*   __restrict__ mask,
    const _Float16* __restrict__ matP,
    const float* __restrict__ wsf,
    float*       __restrict__ wso)   // [0,32): logz ; [32,64): len
{
  const int b = blockIdx.x, lane = threadIdx.x;
  const int c = lane & 15, h = lane >> 4;
  const float* __restrict__ eb = emits + (size_t)b * (S_LEN * LL);

  int len;
  {
    const int* mb = mask + b * S_LEN;
    int cnt = 0;
    #pragma unroll
    for (int i = 0; i < 8; ++i) cnt += (mb[i * 64 + lane] != 0);
    #pragma unroll
    for (int off = 32; off; off >>= 1) cnt += __shfl_xor(cnt, off);
    len = cnt;
  }

  const bool on = (c == 0);
  const h4 HZ = {(_Float16)0, (_Float16)0, (_Float16)0, (_Float16)0};

  // alpha0[k] = E_0[BOS=0][k]
  float la[16];
  #pragma unroll
  for (int K = 0; K < 4; ++K)
    #pragma unroll
    for (int i = 0; i < 4; ++i) la[K * 4 + i] = eb[16 * K + 4 * h + i];
  float mm = la[0];
  #pragma unroll
  for (int i = 1; i < 16; ++i) mm = fmaxf(mm, la[i]);
  const float m0 = fmaxf(fmaxf(bl(mm, 0), bl(mm, 16)), fmaxf(bl(mm, 32), bl(mm, 48)));
  float Lacc = m0;
  h4 bv[4];
  #pragma unroll
  for (int K = 0; K < 4; ++K) {
    U4 y;
    y.u[0] = pk2(__expf(la[4 * K] - m0), __expf(la[4 * K + 1] - m0));
    y.u[1] = pk2(__expf(la[4 * K + 2] - m0), __expf(la[4 * K + 3] - m0));
    bv[K] = on ? y.v : HZ;
  }

  for (int ch = 0; ch < NCH; ++ch) {
    const int n = min(len - (32 * ch + 1), CL);
    if (n < 1) break;  // chunk activity is monotone in ch
    const _Float16* mp = matP + (size_t)(b * NCH + ch) * 4096;
    f4 dv[4];
    #pragma unroll
    for (int I = 0; I < 4; ++I) {
      f4 d = {0.f, 0.f, 0.f, 0.f};
      #pragma unroll
      for (int K = 0; K < 4; ++K) {
        h4 a = *reinterpret_cast<const h4*>(
            mp + (I * 4 + K) * 256 + (c & 3) * 64 + 16 * (c >> 2) + 4 * h);
        d = __builtin_amdgcn_mfma_f32_16x16x16f16(a, bv[K], d, 0, 0, 0);
      }
      dv[I] = d;
    }
    float mx = dv[0][0];
    #pragma unroll
    for (int I = 0; I < 4; ++I)
      #pragma unroll
      for (int u = 0; u < 4; ++u) mx = fmaxf(mx, dv[I][u]);
    const float gm = fmaxf(fmaxf(bl(mx, 0), bl(mx, 16)), fmaxf(bl(mx, 32), bl(mx, 48)));
    const int E = (__float_as_int(gm) >> 23) & 0xFF;
    const float scale = __int_as_float((254 - E) << 23);
    Lacc += (float)(E - 127) * LN2F + wsf[b * NCH + ch];
    #pragma unroll
    for (int I = 0; I < 4; ++I) {
      U4 y;
      y.u[0] = pk2(dv[I][0] * scale, dv[I][1] * scale);
      y.u[1] = pk2(dv[I][2] * scale, dv[I][3] * scale);
      bv[I] = on ? y.v : HZ;
    }
  }

  float qs = 0.f;
  #pragma unroll
  for (int K = 0; K < 4; ++K)
    #pragma unroll
    for (int i = 0; i < 4; ++i) qs += (float)bv[K][i];
  const float q0 = (bl(qs, 0) + bl(qs, 16)) + (bl(qs, 32) + bl(qs, 48));
  if (lane == 0) {
    wso[b]      = Lacc + __logf(q0);
    wso[32 + b] = (float)len;
  }
}

// ---------------- Phase 3: final scalar ----------------
__global__ __launch_bounds__(512) void crf_fin(
    const float* __restrict__ wsf,   // gold at [512,1024)
    const float* __restrict__ wso,   // logz [0,32), len [32,64)
    float* __restrict__ out)
{
  __shared__ float red[8];
  const int tid = threadIdx.x;
  float g = wsf[512 + tid];
  #pragma unroll
  for (int off = 32; off; off >>= 1) g += __shfl_xor(g, off);
  if ((tid & 63) == 0) red[tid >> 6] = g;
  __syncthreads();
  if (tid < 64) {
    float gs = (tid < 8) ? red[tid] : 0.f;
    float lz = (tid < 32) ? wso[tid] : 0.f;
    float ln = (tid < 32) ? wso[32 + tid] : 0.f;
    #pragma unroll
    for (int off = 32; off; off >>= 1) {
      gs += __shfl_xor(gs, off);
      lz += __shfl_xor(lz, off);
      ln += __shfl_xor(ln, off);
    }
    if (tid == 0) out[0] = (lz - gs) / ln;
  }
}

extern "C" void kernel_launch(void* const* d_in, const int* in_sizes, int n_in,
                              void* d_out, int out_size, void* d_ws, size_t ws_size,
                              hipStream_t stream) {
  const float* emits   = (const float*)d_in[0];
  const int*   targets = (const int*)d_in[1];
  const int*   mask    = (const int*)d_in[2];
  float* out = (float*)d_out;

  _Float16* matP = (_Float16*)d_ws;                                   // 4 MB
  float*    wsf  = (float*)((char*)d_ws + (size_t)NCHUNKS * 4096 * 2);
  float*    wso  = wsf + 1024;

  hipLaunchKernelGGL(crf_chunk, dim3(NCHUNKS), dim3(64), 0, stream,
                     emits, targets, mask, matP, wsf);
  hipLaunchKernelGGL(crf_fold, dim3(NB), dim3(64), 0, stream,
                     emits, mask, matP, wsf, wso);
  hipLaunchKernelGGL(crf_fin, dim3(1), dim3(512), 0, stream, wsf, wso, out);
}

// Round 7
// 89.668 us; speedup vs baseline: 4.5518x; 1.1991x over previous
//
#include <hip/hip_runtime.h>
#include <math.h>

// CRF forward loss, B=32, S=512, L=64 — chunked-matrix-product formulation.
// alpha_final^T = M^T_{len-1} ... M^T_1 alpha0^T  with M_s = exp(E_s)*2^-9.
// Phase 1: 512 single-wave blocks; chunk product built BACKWARD
//          (R_new = M^T_s x R_old, s descending) so the fresh matrix's
//          contraction dim is E's stride-1 column -> f4 vector loads, and
//          the D->B rebuild stays lane-local. Identity init. No LDS/barriers.
// Phase 2: 32 single-wave blocks fold 16 chunk matrices into alpha0 as
//          mat-vecs (col-0 trick), depth-1 prefetch of next chunk's frags.
// Phase 3: final scalar reduction.

constexpr int S_LEN   = 512;
constexpr int NB      = 32;
constexpr int NL      = 64;
constexpr int LL      = 4096;
constexpr int CL      = 32;
constexpr int NCH     = 16;
constexpr int NCHUNKS = NB * NCH;  // 512

#define LN2F  0.69314718055994531f
#define PREF  6.2383246250395078f   /* 9*ln2 : M = exp(E)*2^-9 */
#define LOG2E 1.4426950408889634f

typedef _Float16 h4 __attribute__((ext_vector_type(4)));
typedef float    f4 __attribute__((ext_vector_type(4)));
union U4 { unsigned u[2]; h4 v; };

__device__ __forceinline__ float bl(float v, int sl) {
  return __int_as_float(__builtin_amdgcn_readlane(__float_as_int(v), sl));
}
__device__ __forceinline__ unsigned pk2(float a, float b) {
  auto r = __builtin_amdgcn_cvt_pkrtz(a, b);
  return __builtin_bit_cast(unsigned, r);
}
__device__ __forceinline__ float expw(float x) {  // exp(x) * 2^-9
  return exp2f(__builtin_fmaf(x, LOG2E, -9.0f));
}

// ---------------- Phase 1: chunk products (backward) ----------------
__global__ __launch_bounds__(64) void crf_chunk(
    const float* __restrict__ emits,
    const int*   __restrict__ targets,
    const int*   __restrict__ mask,
    _Float16*    __restrict__ matP,   // [512][4096] f16
    float*       __restrict__ wsf)    // [0,512): Lacc ; [512,1024): gold
{
  const int ci   = blockIdx.x;
  const int b    = ci >> 4;
  const int cc   = ci & 15;
  const int lane = threadIdx.x;
  const int c    = lane & 15;
  const int h    = lane >> 4;
  const float* __restrict__ eb = emits + (size_t)b * (S_LEN * LL);

  // sequence length (mask is a contiguous prefix)
  int len;
  {
    const int* mb = mask + b * S_LEN;
    int cnt = 0;
    #pragma unroll
    for (int i = 0; i < 8; ++i) cnt += (mb[i * 64 + lane] != 0);
    #pragma unroll
    for (int off = 32; off; off >>= 1) cnt += __shfl_xor(cnt, off);
    len = cnt;
  }

  // gold partial: emissions s in [32cc, 32cc+32) ∩ [0,len)
  {
    float g = 0.f;
    const int s = 32 * cc + (lane & 31);
    if (lane < 32 && s < len) {
      const int* tb = targets + b * (S_LEN + 1);
      g = eb[(size_t)s * LL + tb[s] * NL + tb[s + 1]];
    }
    #pragma unroll
    for (int off = 32; off; off >>= 1) g += __shfl_xor(g, off);
    if (lane == 0) wsf[512 + ci] = g;
  }

  const int s0 = 32 * cc + 1;          // first transition matrix of chunk
  const int n  = min(len - s0, CL);    // matrices in this chunk
  if (n < 1) return;

  // R = Identity in B-frag layout: bf tile(K,J)[i] = (K==J && 4h+i==c)
  h4 bf[4][4];
  #pragma unroll
  for (int K = 0; K < 4; ++K)
    #pragma unroll
    for (int J = 0; J < 4; ++J) {
      h4 v;
      #pragma unroll
      for (int i = 0; i < 4; ++i)
        v[i] = (_Float16)((K == J && (4 * h + i) == c) ? 1.0f : 0.0f);
      bf[K][J] = v;
    }

  float Lacc = 0.f;
  f4 LB[4][4];  // raw E rows, vector-loaded: LB[I][K] = E[(16I+c)*64 + 16K+4h .. +3]

#define LOADE(S)                                                             \
  do { const float* ep = eb + (size_t)(S) * LL;                              \
    _Pragma("unroll") for (int I = 0; I < 4; ++I) {                          \
      const float* rp = ep + (16 * I + c) * 64 + 4 * h;                      \
      _Pragma("unroll") for (int K = 0; K < 4; ++K)                          \
        LB[I][K] = *reinterpret_cast<const f4*>(rp + 16 * K);                \
    } } while (0)

  LOADE(s0 + n - 1);
  for (int m = 1; m <= n; ++m) {
    // A-frags: af tile(I,K)[i] = M^T[16I+c][16K+4h+i] = expw(LB[I][K][i])
    h4 af[4][4];
    #pragma unroll
    for (int I = 0; I < 4; ++I)
      #pragma unroll
      for (int K = 0; K < 4; ++K) {
        U4 x;
        x.u[0] = pk2(expw(LB[I][K][0]), expw(LB[I][K][1]));
        x.u[1] = pk2(expw(LB[I][K][2]), expw(LB[I][K][3]));
        af[I][K] = x.v;
      }
    if (m < n) LOADE(s0 + n - 1 - m);   // prefetch next (descending s)
    // D = M^T_s x R
    f4 dd[4][4];
    #pragma unroll
    for (int I = 0; I < 4; ++I)
      #pragma unroll
      for (int J = 0; J < 4; ++J) {
        f4 d = {0.f, 0.f, 0.f, 0.f};
        #pragma unroll
        for (int K = 0; K < 4; ++K)
          d = __builtin_amdgcn_mfma_f32_16x16x16f16(af[I][K], bf[K][J], d, 0, 0, 0);
        dd[I][J] = d;
      }
    Lacc += PREF;
    float scale = 1.0f;
    if (((m & 1) == 0) || (m == n)) {
      float mm = dd[0][0][0];
      #pragma unroll
      for (int I = 0; I < 4; ++I)
        #pragma unroll
        for (int J = 0; J < 4; ++J)
          #pragma unroll
          for (int u = 0; u < 4; ++u) mm = fmaxf(mm, dd[I][J][u]);
      #pragma unroll
      for (int off = 32; off; off >>= 1) mm = fmaxf(mm, __shfl_xor(mm, off));
      const int E = (__float_as_int(mm) >> 23) & 0xFF;
      scale = __int_as_float((254 - E) << 23);   // 2^(127-E)
      Lacc += (float)(E - 127) * LN2F;
    }
    // lane-local D->B rebuild: bf tile(K,J)[i] = dd[K][J][i]
    #pragma unroll
    for (int K = 0; K < 4; ++K)
      #pragma unroll
      for (int J = 0; J < 4; ++J) {
        U4 y;
        y.u[0] = pk2(dd[K][J][0] * scale, dd[K][J][1] * scale);
        y.u[1] = pk2(dd[K][J][2] * scale, dd[K][J][3] * scale);
        bf[K][J] = y.v;
      }
  }

  // store R = P^T (B-frag layout), same layout phase 2 expects
  {
    _Float16* mp = matP + (size_t)ci * 4096;
    #pragma unroll
    for (int I = 0; I < 4; ++I)
      #pragma unroll
      for (int J = 0; J < 4; ++J)
        #pragma unroll
        for (int i = 0; i < 4; ++i)
          mp[(I * 4 + J) * 256 + i * 64 + lane] = bf[I][J][i];
  }
  if (lane == 0) wsf[ci] = Lacc;
}

// ---------------- Phase 2: fold chunks into alpha0 ----------------
__global__ __launch_bounds__(64) void crf_fold(
    const float* __restrict__ emits,
    const int*   __restrict__ mask,
    const _Float16* __restrict__ matP,
    const float* __restrict__ wsf,
    float*       __restrict__ wso)   // [0,32): logz ; [32,64): len
{
  const int b = blockIdx.x, lane = threadIdx.x;
  const int c = lane & 15, h = lane >> 4;
  const float* __restrict__ eb = emits + (size_t)b * (S_LEN * LL);

  int len;
  {
    const int* mb = mask + b * S_LEN;
    int cnt = 0;
    #pragma unroll
    for (int i = 0; i < 8; ++i) cnt += (mb[i * 64 + lane] != 0);
    #pragma unroll
    for (int off = 32; off; off >>= 1) cnt += __shfl_xor(cnt, off);
    len = cnt;
  }
  const int nact = (len + 30) >> 5;   // chunks with >=1 matrix (len>=2)

  const bool on = (c == 0);
  const h4 HZ = {(_Float16)0, (_Float16)0, (_Float16)0, (_Float16)0};

  // alpha0[k] = E_0[BOS=0][k]
  float la[16];
  #pragma unroll
  for (int K = 0; K < 4; ++K)
    #pragma unroll
    for (int i = 0; i < 4; ++i) la[K * 4 + i] = eb[16 * K + 4 * h + i];
  float mm = la[0];
  #pragma unroll
  for (int i = 1; i < 16; ++i) mm = fmaxf(mm, la[i]);
  const float m0 = fmaxf(fmaxf(bl(mm, 0), bl(mm, 16)), fmaxf(bl(mm, 32), bl(mm, 48)));
  float Lacc = m0;
  h4 bv[4];
  #pragma unroll
  for (int K = 0; K < 4; ++K) {
    U4 y;
    y.u[0] = pk2(__expf(la[4 * K] - m0), __expf(la[4 * K + 1] - m0));
    y.u[1] = pk2(__expf(la[4 * K + 2] - m0), __expf(la[4 * K + 3] - m0));
    bv[K] = on ? y.v : HZ;
  }

  h4 A0[4][4], A1[4][4];

#define LOADA(AF, CH)                                                        \
  do { const _Float16* mp = matP + (size_t)(b * NCH + (CH)) * 4096;          \
    _Pragma("unroll") for (int I = 0; I < 4; ++I)                            \
      _Pragma("unroll") for (int K = 0; K < 4; ++K)                          \
        AF[I][K] = *reinterpret_cast<const h4*>(                             \
            mp + (I * 4 + K) * 256 + (c & 3) * 64 + 16 * (c >> 2) + 4 * h);  \
  } while (0)

#define FOLD(AF, CH)                                                         \
  do { f4 dv[4];                                                             \
    _Pragma("unroll") for (int I = 0; I < 4; ++I) {                          \
      f4 d = {0.f, 0.f, 0.f, 0.f};                                           \
      _Pragma("unroll") for (int K = 0; K < 4; ++K)                          \
        d = __builtin_amdgcn_mfma_f32_16x16x16f16(AF[I][K], bv[K], d, 0, 0, 0); \
      dv[I] = d;                                                             \
    }                                                                        \
    float mx = dv[0][0];                                                     \
    _Pragma("unroll") for (int I = 0; I < 4; ++I)                            \
      _Pragma("unroll") for (int u = 0; u < 4; ++u) mx = fmaxf(mx, dv[I][u]); \
    const float gm = fmaxf(fmaxf(bl(mx, 0), bl(mx, 16)),                     \
                           fmaxf(bl(mx, 32), bl(mx, 48)));                   \
    const int E = (__float_as_int(gm) >> 23) & 0xFF;                         \
    const float scale = __int_as_float((254 - E) << 23);                     \
    Lacc += (float)(E - 127) * LN2F + wsf[b * NCH + (CH)];                   \
    _Pragma("unroll") for (int I = 0; I < 4; ++I) {                          \
      U4 y;                                                                  \
      y.u[0] = pk2(dv[I][0] * scale, dv[I][1] * scale);                      \
      y.u[1] = pk2(dv[I][2] * scale, dv[I][3] * scale);                      \
      bv[I] = on ? y.v : HZ;                                                 \
    } } while (0)

  LOADA(A0, 0);
  for (int ch = 0; ch < nact; ++ch) {
    if (ch & 1) { if (ch + 1 < nact) LOADA(A0, ch + 1); FOLD(A1, ch); }
    else        { if (ch + 1 < nact) LOADA(A1, ch + 1); FOLD(A0, ch); }
  }

  float qs = 0.f;
  #pragma unroll
  for (int K = 0; K < 4; ++K)
    #pragma unroll
    for (int i = 0; i < 4; ++i) qs += (float)bv[K][i];
  const float q0 = (bl(qs, 0) + bl(qs, 16)) + (bl(qs, 32) + bl(qs, 48));
  if (lane == 0) {
    wso[b]      = Lacc + __logf(q0);
    wso[32 + b] = (float)len;
  }
}

// ---------------- Phase 3: final scalar ----------------
__global__ __launch_bounds__(512) void crf_fin(
    const float* __restrict__ wsf,   // gold at [512,1024)
    const float* __restrict__ wso,   // logz [0,32), len [32,64)
    float* __restrict__ out)
{
  __shared__ float red[8];
  const int tid = threadIdx.x;
  float g = wsf[512 + tid];
  #pragma unroll
  for (int off = 32; off; off >>= 1) g += __shfl_xor(g, off);
  if ((tid & 63) == 0) red[tid >> 6] = g;
  __syncthreads();
  if (tid < 64) {
    float gs = (tid < 8) ? red[tid] : 0.f;
    float lz = (tid < 32) ? wso[tid] : 0.f;
    float ln = (tid < 32) ? wso[32 + tid] : 0.f;
    #pragma unroll
    for (int off = 32; off; off >>= 1) {
      gs += __shfl_xor(gs, off);
      lz += __shfl_xor(lz, off);
      ln += __shfl_xor(ln, off);
    }
    if (tid == 0) out[0] = (lz - gs) / ln;
  }
}

extern "C" void kernel_launch(void* const* d_in, const int* in_sizes, int n_in,
                              void* d_out, int out_size, void* d_ws, size_t ws_size,
                              hipStream_t stream) {
  const float* emits   = (const float*)d_in[0];
  const int*   targets = (const int*)d_in[1];
  const int*   mask    = (const int*)d_in[2];
  float* out = (float*)d_out;

  _Float16* matP = (_Float16*)d_ws;                                   // 4 MB
  float*    wsf  = (float*)((char*)d_ws + (size_t)NCHUNKS * 4096 * 2);
  float*    wso  = wsf + 1024;

  hipLaunchKernelGGL(crf_chunk, dim3(NCHUNKS), dim3(64), 0, stream,
                     emits, targets, mask, matP, wsf);
  hipLaunchKernelGGL(crf_fold, dim3(NB), dim3(64), 0, stream,
                     emits, mask, matP, wsf, wso);
  hipLaunchKernelGGL(crf_fin, dim3(1), dim3(512), 0, stream, wsf, wso, out);
}

// Round 8
// 86.312 us; speedup vs baseline: 4.7288x; 1.0389x over previous
//
#include <hip/hip_runtime.h>
#include <math.h>

// CRF forward loss, B=32, S=512, L=64 — chunked-matrix-product formulation.
// alpha_final^T = M^T_{len-1} ... M^T_1 alpha0^T, M_s = exp(E_s - PREF).
// PREF = ln(64)+0.5 makes E[col-sum of M] = 1 for N(0,1) inputs -> near-zero
// magnitude drift -> renorm needed only every 8 steps (exponent trick).
// Phase 1: 512 single-wave blocks; backward product (fresh matrix contracts
//          over E's stride-1 column -> f4 vector loads; lane-local D->B).
//          J-halved accumulators keep VGPR ~<190 (round-7 full dd likely
//          spilled: ~540 MB scratch traffic explains the 55 us gap).
// Phase 2: 32 single-wave blocks fold 16 chunk matrices into alpha0.
// Phase 3: final scalar reduction.

constexpr int S_LEN   = 512;
constexpr int NB      = 32;
constexpr int NL      = 64;
constexpr int LL      = 4096;
constexpr int CL      = 32;
constexpr int NCH     = 16;
constexpr int NCHUNKS = NB * NCH;  // 512

#define LN2F  0.69314718055994531f
#define PREF  4.6588830833596715f   /* ln(64)+0.5 : M = exp(E)*e^-PREF */
#define LOG2E 1.4426950408889634f
#define PREF2 6.7212503954271743f   /* PREF*log2(e): exp2 argument shift */

typedef _Float16 h4 __attribute__((ext_vector_type(4)));
typedef float    f4 __attribute__((ext_vector_type(4)));
union U4 { unsigned u[2]; h4 v; };

__device__ __forceinline__ float bl(float v, int sl) {
  return __int_as_float(__builtin_amdgcn_readlane(__float_as_int(v), sl));
}
__device__ __forceinline__ unsigned pk2(float a, float b) {
  auto r = __builtin_amdgcn_cvt_pkrtz(a, b);
  return __builtin_bit_cast(unsigned, r);
}
__device__ __forceinline__ float expw(float x) {  // exp(x)*e^-PREF
  return exp2f(__builtin_fmaf(x, LOG2E, -PREF2));
}

// ---------------- Phase 1: chunk products (backward, J-halved) ----------------
__global__ __launch_bounds__(64) void crf_chunk(
    const float* __restrict__ emits,
    const int*   __restrict__ targets,
    const int*   __restrict__ mask,
    _Float16*    __restrict__ matP,   // [512][4096] f16
    float*       __restrict__ wsf)    // [0,512): Lacc ; [512,1024): gold
{
  const int ci   = blockIdx.x;
  const int b    = ci >> 4;
  const int cc   = ci & 15;
  const int lane = threadIdx.x;
  const int c    = lane & 15;
  const int h    = lane >> 4;
  const float* __restrict__ eb = emits + (size_t)b * (S_LEN * LL);

  // sequence length (mask is a contiguous prefix)
  int len;
  {
    const int* mb = mask + b * S_LEN;
    int cnt = 0;
    #pragma unroll
    for (int i = 0; i < 8; ++i) cnt += (mb[i * 64 + lane] != 0);
    #pragma unroll
    for (int off = 32; off; off >>= 1) cnt += __shfl_xor(cnt, off);
    len = cnt;
  }

  // gold partial: emissions s in [32cc, 32cc+32) ∩ [0,len)
  {
    float g = 0.f;
    const int s = 32 * cc + (lane & 31);
    if (lane < 32 && s < len) {
      const int* tb = targets + b * (S_LEN + 1);
      g = eb[(size_t)s * LL + tb[s] * NL + tb[s + 1]];
    }
    #pragma unroll
    for (int off = 32; off; off >>= 1) g += __shfl_xor(g, off);
    if (lane == 0) wsf[512 + ci] = g;
  }

  const int s0 = 32 * cc + 1;
  const int n  = min(len - s0, CL);
  if (n < 1) return;

  // R = Identity in B-frag layout: bf tile(K,J)[i] = (K==J && 4h+i==c)
  h4 bf[4][4];
  #pragma unroll
  for (int K = 0; K < 4; ++K)
    #pragma unroll
    for (int J = 0; J < 4; ++J) {
      h4 v;
      #pragma unroll
      for (int i = 0; i < 4; ++i)
        v[i] = (_Float16)((K == J && (4 * h + i) == c) ? 1.0f : 0.0f);
      bf[K][J] = v;
    }

  float Lacc = 0.f;
  f4 LB[4][4];  // raw E, vector-loaded

#define LOADE(S)                                                             \
  do { const float* ep = eb + (size_t)(S) * LL;                              \
    _Pragma("unroll") for (int I = 0; I < 4; ++I) {                          \
      const float* rp = ep + (16 * I + c) * 64 + 4 * h;                      \
      _Pragma("unroll") for (int K = 0; K < 4; ++K)                          \
        LB[I][K] = *reinterpret_cast<const f4*>(rp + 16 * K);                \
    } } while (0)

  LOADE(s0 + n - 1);
  for (int m = 1; m <= n; ++m) {
    // af tile(I,K)[i] = expw(LB[I][K][i])
    h4 af[4][4];
    #pragma unroll
    for (int I = 0; I < 4; ++I)
      #pragma unroll
      for (int K = 0; K < 4; ++K) {
        U4 x;
        x.u[0] = pk2(expw(LB[I][K][0]), expw(LB[I][K][1]));
        x.u[1] = pk2(expw(LB[I][K][2]), expw(LB[I][K][3]));
        af[I][K] = x.v;
      }
    if (m < n) LOADE(s0 + n - 1 - m);   // prefetch next (descending s)

    const bool rn = ((m & 7) == 0) || (m == n);
    float mh = 0.f;

    // ---- half 0: J in {0,1} ----
    {
      f4 dh[4][2];
      #pragma unroll
      for (int I = 0; I < 4; ++I)
        #pragma unroll
        for (int J = 0; J < 2; ++J) {
          f4 d = {0.f, 0.f, 0.f, 0.f};
          #pragma unroll
          for (int K = 0; K < 4; ++K)
            d = __builtin_amdgcn_mfma_f32_16x16x16f16(af[I][K], bf[K][J], d, 0, 0, 0);
          dh[I][J] = d;
        }
      if (rn) {
        #pragma unroll
        for (int I = 0; I < 4; ++I)
          #pragma unroll
          for (int J = 0; J < 2; ++J)
            #pragma unroll
            for (int u = 0; u < 4; ++u) mh = fmaxf(mh, dh[I][J][u]);
      }
      #pragma unroll
      for (int K = 0; K < 4; ++K)
        #pragma unroll
        for (int J = 0; J < 2; ++J) {
          U4 y;
          y.u[0] = pk2(dh[K][J][0], dh[K][J][1]);
          y.u[1] = pk2(dh[K][J][2], dh[K][J][3]);
          bf[K][J] = y.v;
        }
    }
    // ---- half 1: J in {2,3} ----
    {
      f4 dh[4][2];
      #pragma unroll
      for (int I = 0; I < 4; ++I)
        #pragma unroll
        for (int J = 0; J < 2; ++J) {
          f4 d = {0.f, 0.f, 0.f, 0.f};
          #pragma unroll
          for (int K = 0; K < 4; ++K)
            d = __builtin_amdgcn_mfma_f32_16x16x16f16(af[I][K], bf[K][J + 2], d, 0, 0, 0);
          dh[I][J] = d;
        }
      if (rn) {
        #pragma unroll
        for (int I = 0; I < 4; ++I)
          #pragma unroll
          for (int J = 0; J < 2; ++J)
            #pragma unroll
            for (int u = 0; u < 4; ++u) mh = fmaxf(mh, dh[I][J][u]);
      }
      #pragma unroll
      for (int K = 0; K < 4; ++K)
        #pragma unroll
        for (int J = 0; J < 2; ++J) {
          U4 y;
          y.u[0] = pk2(dh[K][J][0], dh[K][J][1]);
          y.u[1] = pk2(dh[K][J][2], dh[K][J][3]);
          bf[K][J + 2] = y.v;
        }
    }

    Lacc += PREF;
    if (rn) {
      #pragma unroll
      for (int off = 32; off; off >>= 1) mh = fmaxf(mh, __shfl_xor(mh, off));
      const int E = (__float_as_int(mh) >> 23) & 0xFF;
      const _Float16 hs = (_Float16)__int_as_float((254 - E) << 23);  // 2^(127-E)
      const h4 hv = {hs, hs, hs, hs};
      #pragma unroll
      for (int K = 0; K < 4; ++K)
        #pragma unroll
        for (int J = 0; J < 4; ++J) bf[K][J] *= hv;   // exact pow2 scale
      Lacc += (float)(E - 127) * LN2F;
    }
  }

  // store R = P^T (B-frag layout)
  {
    _Float16* mp = matP + (size_t)ci * 4096;
    #pragma unroll
    for (int I = 0; I < 4; ++I)
      #pragma unroll
      for (int J = 0; J < 4; ++J)
        #pragma unroll
        for (int i = 0; i < 4; ++i)
          mp[(I * 4 + J) * 256 + i * 64 + lane] = bf[I][J][i];
  }
  if (lane == 0) wsf[ci] = Lacc;
}

// ---------------- Phase 2: fold chunks into alpha0 ----------------
__global__ __launch_bounds__(64) void crf_fold(
    const float* __restrict__ emits,
    const int*   __restrict__ mask,
    const _Float16* __restrict__ matP,
    const float* __restrict__ wsf,
    float*       __restrict__ wso)   // [0,32): logz ; [32,64): len
{
  const int b = blockIdx.x, lane = threadIdx.x;
  const int c = lane & 15, h = lane >> 4;
  const float* __restrict__ eb = emits + (size_t)b * (S_LEN * LL);

  int len;
  {
    const int* mb = mask + b * S_LEN;
    int cnt = 0;
    #pragma unroll
    for (int i = 0; i < 8; ++i) cnt += (mb[i * 64 + lane] != 0);
    #pragma unroll
    for (int off = 32; off; off >>= 1) cnt += __shfl_xor(cnt, off);
    len = cnt;
  }
  const int nact = (len + 30) >> 5;

  const bool on = (c == 0);
  const h4 HZ = {(_Float16)0, (_Float16)0, (_Float16)0, (_Float16)0};

  // alpha0[k] = E_0[BOS=0][k]
  float la[16];
  #pragma unroll
  for (int K = 0; K < 4; ++K)
    #pragma unroll
    for (int i = 0; i < 4; ++i) la[K * 4 + i] = eb[16 * K + 4 * h + i];
  float mm = la[0];
  #pragma unroll
  for (int i = 1; i < 16; ++i) mm = fmaxf(mm, la[i]);
  const float m0 = fmaxf(fmaxf(bl(mm, 0), bl(mm, 16)), fmaxf(bl(mm, 32), bl(mm, 48)));
  float Lacc = m0;
  h4 bv[4];
  #pragma unroll
  for (int K = 0; K < 4; ++K) {
    U4 y;
    y.u[0] = pk2(__expf(la[4 * K] - m0), __expf(la[4 * K + 1] - m0));
    y.u[1] = pk2(__expf(la[4 * K + 2] - m0), __expf(la[4 * K + 3] - m0));
    bv[K] = on ? y.v : HZ;
  }

  h4 A0[4][4], A1[4][4];

#define LOADA(AF, CH)                                                        \
  do { const _Float16* mp = matP + (size_t)(b * NCH + (CH)) * 4096;          \
    _Pragma("unroll") for (int I = 0; I < 4; ++I)                            \
      _Pragma("unroll") for (int K = 0; K < 4; ++K)                          \
        AF[I][K] = *reinterpret_cast<const h4*>(                             \
            mp + (I * 4 + K) * 256 + (c & 3) * 64 + 16 * (c >> 2) + 4 * h);  \
  } while (0)

#define FOLD(AF, CH)                                                         \
  do { f4 dv[4];                                                             \
    _Pragma("unroll") for (int I = 0; I < 4; ++I) {                          \
      f4 d = {0.f, 0.f, 0.f, 0.f};                                           \
      _Pragma("unroll") for (int K = 0; K < 4; ++K)                          \
        d = __builtin_amdgcn_mfma_f32_16x16x16f16(AF[I][K], bv[K], d, 0, 0, 0); \
      dv[I] = d;                                                             \
    }                                                                        \
    float mx = dv[0][0];                                                     \
    _Pragma("unroll") for (int I = 0; I < 4; ++I)                            \
      _Pragma("unroll") for (int u = 0; u < 4; ++u) mx = fmaxf(mx, dv[I][u]); \
    const float gm = fmaxf(fmaxf(bl(mx, 0), bl(mx, 16)),                     \
                           fmaxf(bl(mx, 32), bl(mx, 48)));                   \
    const int E = (__float_as_int(gm) >> 23) & 0xFF;                         \
    const float scale = __int_as_float((254 - E) << 23);                     \
    Lacc += (float)(E - 127) * LN2F + wsf[b * NCH + (CH)];                   \
    _Pragma("unroll") for (int I = 0; I < 4; ++I) {                          \
      U4 y;                                                                  \
      y.u[0] = pk2(dv[I][0] * scale, dv[I][1] * scale);                      \
      y.u[1] = pk2(dv[I][2] * scale, dv[I][3] * scale);                      \
      bv[I] = on ? y.v : HZ;                                                 \
    } } while (0)

  LOADA(A0, 0);
  for (int ch = 0; ch < nact; ++ch) {
    if (ch & 1) { if (ch + 1 < nact) LOADA(A0, ch + 1); FOLD(A1, ch); }
    else        { if (ch + 1 < nact) LOADA(A1, ch + 1); FOLD(A0, ch); }
  }

  float qs = 0.f;
  #pragma unroll
  for (int K = 0; K < 4; ++K)
    #pragma unroll
    for (int i = 0; i < 4; ++i) qs += (float)bv[K][i];
  const float q0 = (bl(qs, 0) + bl(qs, 16)) + (bl(qs, 32) + bl(qs, 48));
  if (lane == 0) {
    wso[b]      = Lacc + __logf(q0);
    wso[32 + b] = (float)len;
  }
}

// ---------------- Phase 3: final scalar ----------------
__global__ __launch_bounds__(512) void crf_fin(
    const float* __restrict__ wsf,   // gold at [512,1024)
    const float* __restrict__ wso,   // logz [0,32), len [32,64)
    float* __restrict__ out)
{
  __shared__ float red[8];
  const int tid = threadIdx.x;
  float g = wsf[512 + tid];
  #pragma unroll
  for (int off = 32; off; off >>= 1) g += __shfl_xor(g, off);
  if ((tid & 63) == 0) red[tid >> 6] = g;
  __syncthreads();
  if (tid < 64) {
    float gs = (tid < 8) ? red[tid] : 0.f;
    float lz = (tid < 32) ? wso[tid] : 0.f;
    float ln = (tid < 32) ? wso[32 + tid] : 0.f;
    #pragma unroll
    for (int off = 32; off; off >>= 1) {
      gs += __shfl_xor(gs, off);
      lz += __shfl_xor(lz, off);
      ln += __shfl_xor(ln, off);
    }
    if (tid == 0) out[0] = (lz - gs) / ln;
  }
}

extern "C" void kernel_launch(void* const* d_in, const int* in_sizes, int n_in,
                              void* d_out, int out_size, void* d_ws, size_t ws_size,
                              hipStream_t stream) {
  const float* emits   = (const float*)d_in[0];
  const int*   targets = (const int*)d_in[1];
  const int*   mask    = (const int*)d_in[2];
  float* out = (float*)d_out;

  _Float16* matP = (_Float16*)d_ws;                                   // 4 MB
  float*    wsf  = (float*)((char*)d_ws + (size_t)NCHUNKS * 4096 * 2);
  float*    wso  = wsf + 1024;

  hipLaunchKernelGGL(crf_chunk, dim3(NCHUNKS), dim3(64), 0, stream,
                     emits, targets, mask, matP, wsf);
  hipLaunchKernelGGL(crf_fold, dim3(NB), dim3(64), 0, stream,
                     emits, mask, matP, wsf, wso);
  hipLaunchKernelGGL(crf_fin, dim3(1), dim3(512), 0, stream, wsf, wso, out);
}

// Round 10
// 77.115 us; speedup vs baseline: 5.2928x; 1.1193x over previous
//
#include <hip/hip_runtime.h>
#include <math.h>

// CRF forward loss, B=32, S=512, L=64 — chunked-matrix-product formulation.
// alpha_final^T = M^T_{len-1} ... M^T_1 alpha0^T, M_s = exp(E_s - PREF).
// Round 9: phase-1 occupancy attack. CL=16 -> 1024 single-wave blocks
// (4 waves/CU, all SIMDs), native __expf, af-fragment double-buffering.
// Fold+fin fused into one kernel (device-scope done-counter).

constexpr int S_LEN   = 512;
constexpr int NB      = 32;
constexpr int NL      = 64;
constexpr int LL      = 4096;
constexpr int CL      = 16;
constexpr int NCH     = 32;            // chunks per batch
constexpr int NCHUNKS = NB * NCH;      // 1024

#define LN2F 0.69314718055994531f
#define PREF 4.6588830833596715f       /* ln(64)+0.5 : M = exp(E)*e^-PREF */

typedef _Float16 h4 __attribute__((ext_vector_type(4)));
typedef float    f4 __attribute__((ext_vector_type(4)));
union U4 { unsigned u[2]; h4 v; };

__device__ __forceinline__ float bl(float v, int sl) {
  return __int_as_float(__builtin_amdgcn_readlane(__float_as_int(v), sl));
}
__device__ __forceinline__ unsigned pk2(float a, float b) {
  auto r = __builtin_amdgcn_cvt_pkrtz(a, b);
  return __builtin_bit_cast(unsigned, r);
}
__device__ __forceinline__ float expw(float x) {   // exp(x)*e^-PREF, native
  return __expf(x - PREF);
}

// ---------------- Phase 1: chunk products (backward, af-dbuf) ----------------
__global__ __launch_bounds__(64) void crf_chunk(
    const float* __restrict__ emits,
    const int*   __restrict__ targets,
    const int*   __restrict__ mask,
    _Float16*    __restrict__ matP,   // [1024][4096] f16
    float*       __restrict__ wsf)    // [0,1024): Lacc ; [1024,2048): gold
{
  const int ci   = blockIdx.x;
  const int b    = ci >> 5;
  const int cc   = ci & 31;
  const int lane = threadIdx.x;
  const int c    = lane & 15;
  const int h    = lane >> 4;
  const float* __restrict__ eb = emits + (size_t)b * (S_LEN * LL);

  // sequence length (mask is a contiguous prefix)
  int len;
  {
    const int* mb = mask + b * S_LEN;
    int cnt = 0;
    #pragma unroll
    for (int i = 0; i < 8; ++i) cnt += (mb[i * 64 + lane] != 0);
    #pragma unroll
    for (int off = 32; off; off >>= 1) cnt += __shfl_xor(cnt, off);
    len = cnt;
  }

  // gold partial: emissions s in [16cc, 16cc+16) ∩ [0,len)
  {
    float g = 0.f;
    const int s = 16 * cc + (lane & 15);
    if (lane < 16 && s < len) {
      const int* tb = targets + b * (S_LEN + 1);
      g = eb[(size_t)s * LL + tb[s] * NL + tb[s + 1]];
    }
    #pragma unroll
    for (int off = 32; off; off >>= 1) g += __shfl_xor(g, off);
    if (lane == 0) wsf[NCHUNKS + ci] = g;
  }

  const int s0 = 16 * cc + 1;
  const int n  = min(len - s0, CL);
  if (n < 1) return;

  // R = Identity in B-frag layout: bf tile(K,J)[i] = (K==J && 4h+i==c)
  h4 bf[4][4];
  #pragma unroll
  for (int K = 0; K < 4; ++K)
    #pragma unroll
    for (int J = 0; J < 4; ++J) {
      h4 v;
      #pragma unroll
      for (int i = 0; i < 4; ++i)
        v[i] = (_Float16)((K == J && (4 * h + i) == c) ? 1.0f : 0.0f);
      bf[K][J] = v;
    }

  float Lacc = 0.f;
  f4 LB[4][4];          // raw E, vector-loaded
  h4 afA[4][4], afB[4][4];

#define LOADE(S)                                                             \
  do { const float* ep = eb + (size_t)(S) * LL;                              \
    _Pragma("unroll") for (int I = 0; I < 4; ++I) {                          \
      const float* rp = ep + (16 * I + c) * 64 + 4 * h;                      \
      _Pragma("unroll") for (int K = 0; K < 4; ++K)                          \
        LB[I][K] = *reinterpret_cast<const f4*>(rp + 16 * K);                \
    } } while (0)

#define BUILDAF(AF)                                                          \
  do { _Pragma("unroll") for (int I = 0; I < 4; ++I)                         \
    _Pragma("unroll") for (int K = 0; K < 4; ++K) {                          \
      U4 x;                                                                  \
      x.u[0] = pk2(expw(LB[I][K][0]), expw(LB[I][K][1]));                    \
      x.u[1] = pk2(expw(LB[I][K][2]), expw(LB[I][K][3]));                    \
      AF[I][K] = x.v;                                                        \
    } } while (0)

#define STEPM(AC, AN, M)                                                     \
  do { if ((M) <= n) {                                                       \
    const bool rn = ((((M) & 7) == 0) || ((M) == n));                        \
    float mh = 0.f;                                                          \
    { /* half 0: J in {0,1} */                                               \
      f4 dh[4][2];                                                           \
      _Pragma("unroll") for (int I = 0; I < 4; ++I)                          \
        _Pragma("unroll") for (int J = 0; J < 2; ++J) {                      \
          f4 d = {0.f, 0.f, 0.f, 0.f};                                       \
          _Pragma("unroll") for (int K = 0; K < 4; ++K)                      \
            d = __builtin_amdgcn_mfma_f32_16x16x16f16(AC[I][K], bf[K][J], d, 0, 0, 0); \
          dh[I][J] = d;                                                      \
        }                                                                    \
      if (rn) {                                                              \
        _Pragma("unroll") for (int I = 0; I < 4; ++I)                        \
          _Pragma("unroll") for (int J = 0; J < 2; ++J)                      \
            _Pragma("unroll") for (int u = 0; u < 4; ++u)                    \
              mh = fmaxf(mh, dh[I][J][u]);                                   \
      }                                                                      \
      _Pragma("unroll") for (int K = 0; K < 4; ++K)                          \
        _Pragma("unroll") for (int J = 0; J < 2; ++J) {                      \
          U4 y;                                                              \
          y.u[0] = pk2(dh[K][J][0], dh[K][J][1]);                            \
          y.u[1] = pk2(dh[K][J][2], dh[K][J][3]);                            \
          bf[K][J] = y.v;                                                    \
        }                                                                    \
    }                                                                        \
    { /* half 1: J in {2,3} */                                               \
      f4 dh[4][2];                                                           \
      _Pragma("unroll") for (int I = 0; I < 4; ++I)                          \
        _Pragma("unroll") for (int J = 0; J < 2; ++J) {                      \
          f4 d = {0.f, 0.f, 0.f, 0.f};                                       \
          _Pragma("unroll") for (int K = 0; K < 4; ++K)                      \
            d = __builtin_amdgcn_mfma_f32_16x16x16f16(AC[I][K], bf[K][J + 2], d, 0, 0, 0); \
          dh[I][J] = d;                                                      \
        }                                                                    \
      if (rn) {                                                              \
        _Pragma("unroll") for (int I = 0; I < 4; ++I)                        \
          _Pragma("unroll") for (int J = 0; J < 2; ++J)                      \
            _Pragma("unroll") for (int u = 0; u < 4; ++u)                    \
              mh = fmaxf(mh, dh[I][J][u]);                                   \
      }                                                                      \
      _Pragma("unroll") for (int K = 0; K < 4; ++K)                          \
        _Pragma("unroll") for (int J = 0; J < 2; ++J) {                      \
          U4 y;                                                              \
          y.u[0] = pk2(dh[K][J][0], dh[K][J][1]);                            \
          y.u[1] = pk2(dh[K][J][2], dh[K][J][3]);                            \
          bf[K][J + 2] = y.v;                                                \
        }                                                                    \
    }                                                                        \
    Lacc += PREF;                                                            \
    if (rn) {                                                                \
      _Pragma("unroll") for (int off = 32; off; off >>= 1)                   \
        mh = fmaxf(mh, __shfl_xor(mh, off));                                 \
      const int E = (__float_as_int(mh) >> 23) & 0xFF;                       \
      const _Float16 hs = (_Float16)__int_as_float((254 - E) << 23);         \
      const h4 hv = {hs, hs, hs, hs};                                        \
      _Pragma("unroll") for (int K = 0; K < 4; ++K)                          \
        _Pragma("unroll") for (int J = 0; J < 4; ++J) bf[K][J] *= hv;        \
      Lacc += (float)(E - 127) * LN2F;                                       \
    }                                                                        \
    if ((M) < n) {                                                           \
      BUILDAF(AN);                         /* from LB (step M+1 matrix) */   \
      if ((M) + 1 < n) LOADE(s0 + n - 2 - (M));  /* step M+2 matrix */       \
    }                                                                        \
  } } while (0)

  LOADE(s0 + n - 1);            // step-1 matrix
  BUILDAF(afA);
  if (n > 1) LOADE(s0 + n - 2); // step-2 matrix
  for (int m = 1; m <= n; m += 2) {
    STEPM(afA, afB, m);
    STEPM(afB, afA, m + 1);
  }

  // store R = P^T (B-frag layout)
  {
    _Float16* mp = matP + (size_t)ci * 4096;
    #pragma unroll
    for (int I = 0; I < 4; ++I)
      #pragma unroll
      for (int J = 0; J < 4; ++J)
        #pragma unroll
        for (int i = 0; i < 4; ++i)
          mp[(I * 4 + J) * 256 + i * 64 + lane] = bf[I][J][i];
  }
  if (lane == 0) wsf[ci] = Lacc;
}

// ---------------- Phase 2: fold chunks into alpha0 (+ fused finale) --------
__global__ __launch_bounds__(64) void crf_fold(
    const float* __restrict__ emits,
    const int*   __restrict__ mask,
    const _Float16* __restrict__ matP,
    const float* __restrict__ wsf,
    float*       __restrict__ wso,   // [0,32): logz ; [32,64): len
    int*         __restrict__ done,
    float*       __restrict__ out)
{
  const int b = blockIdx.x, lane = threadIdx.x;
  const int c = lane & 15, h = lane >> 4;
  const float* __restrict__ eb = emits + (size_t)b * (S_LEN * LL);

  int len;
  {
    const int* mb = mask + b * S_LEN;
    int cnt = 0;
    #pragma unroll
    for (int i = 0; i < 8; ++i) cnt += (mb[i * 64 + lane] != 0);
    #pragma unroll
    for (int off = 32; off; off >>= 1) cnt += __shfl_xor(cnt, off);
    len = cnt;
  }
  const int nact = (len + 14) >> 4;   // chunks with >=1 matrix (len>=2)

  const bool on = (c == 0);
  const h4 HZ = {(_Float16)0, (_Float16)0, (_Float16)0, (_Float16)0};

  // alpha0[k] = E_0[BOS=0][k]
  float la[16];
  #pragma unroll
  for (int K = 0; K < 4; ++K)
    #pragma unroll
    for (int i = 0; i < 4; ++i) la[K * 4 + i] = eb[16 * K + 4 * h + i];
  float mm = la[0];
  #pragma unroll
  for (int i = 1; i < 16; ++i) mm = fmaxf(mm, la[i]);
  const float m0 = fmaxf(fmaxf(bl(mm, 0), bl(mm, 16)), fmaxf(bl(mm, 32), bl(mm, 48)));
  float Lacc = m0;
  h4 bv[4];
  #pragma unroll
  for (int K = 0; K < 4; ++K) {
    U4 y;
    y.u[0] = pk2(__expf(la[4 * K] - m0), __expf(la[4 * K + 1] - m0));
    y.u[1] = pk2(__expf(la[4 * K + 2] - m0), __expf(la[4 * K + 3] - m0));
    bv[K] = on ? y.v : HZ;
  }

  h4 A0[4][4], A1[4][4];

#define LOADA(AF, CH)                                                        \
  do { const _Float16* mp = matP + (size_t)(b * NCH + (CH)) * 4096;          \
    _Pragma("unroll") for (int I = 0; I < 4; ++I)                            \
      _Pragma("unroll") for (int K = 0; K < 4; ++K)                          \
        AF[I][K] = *reinterpret_cast<const h4*>(                             \
            mp + (I * 4 + K) * 256 + (c & 3) * 64 + 16 * (c >> 2) + 4 * h);  \
  } while (0)

#define FOLD(AF, CH)                                                         \
  do { f4 dv[4];                                                             \
    _Pragma("unroll") for (int I = 0; I < 4; ++I) {                          \
      f4 d = {0.f, 0.f, 0.f, 0.f};                                           \
      _Pragma("unroll") for (int K = 0; K < 4; ++K)                          \
        d = __builtin_amdgcn_mfma_f32_16x16x16f16(AF[I][K], bv[K], d, 0, 0, 0); \
      dv[I] = d;                                                             \
    }                                                                        \
    float mx = dv[0][0];                                                     \
    _Pragma("unroll") for (int I = 0; I < 4; ++I)                            \
      _Pragma("unroll") for (int u = 0; u < 4; ++u) mx = fmaxf(mx, dv[I][u]); \
    const float gm = fmaxf(fmaxf(bl(mx, 0), bl(mx, 16)),                     \
                           fmaxf(bl(mx, 32), bl(mx, 48)));                   \
    const int E = (__float_as_int(gm) >> 23) & 0xFF;                         \
    const float scale = __int_as_float((254 - E) << 23);                     \
    Lacc += (float)(E - 127) * LN2F + wsf[b * NCH + (CH)];                   \
    _Pragma("unroll") for (int I = 0; I < 4; ++I) {                          \
      U4 y;                                                                  \
      y.u[0] = pk2(dv[I][0] * scale, dv[I][1] * scale);                      \
      y.u[1] = pk2(dv[I][2] * scale, dv[I][3] * scale);                      \
      bv[I] = on ? y.v : HZ;                                                 \
    } } while (0)

  LOADA(A0, 0);
  for (int ch = 0; ch < nact; ++ch) {
    if (ch & 1) { if (ch + 1 < nact) LOADA(A0, ch + 1); FOLD(A1, ch); }
    else        { if (ch + 1 < nact) LOADA(A1, ch + 1); FOLD(A0, ch); }
  }

  float qs = 0.f;
  #pragma unroll
  for (int K = 0; K < 4; ++K)
    #pragma unroll
    for (int i = 0; i < 4; ++i) qs += (float)bv[K][i];
  const float q0 = (bl(qs, 0) + bl(qs, 16)) + (bl(qs, 32) + bl(qs, 48));
  if (lane == 0) {
    wso[b]      = Lacc + __logf(q0);
    wso[32 + b] = (float)len;
  }

  // ---- fused finale: last block to finish reduces everything ----
  __threadfence();
  int isLast = 0;
  if (lane == 0) isLast = (atomicAdd(done, 1) == NB - 1);
  isLast = __shfl(isLast, 0);
  if (isLast) {
    __threadfence();
    const float* gold = wsf + NCHUNKS;
    float gs = 0.f;
    #pragma unroll
    for (int i = 0; i < NCHUNKS / 64; ++i) gs += gold[i * 64 + lane];
    float lz = (lane < NB) ? wso[lane] : 0.f;
    float ln = (lane < NB) ? wso[32 + lane] : 0.f;
    #pragma unroll
    for (int off = 32; off; off >>= 1) {
      gs += __shfl_xor(gs, off);
      lz += __shfl_xor(lz, off);
      ln += __shfl_xor(ln, off);
    }
    if (lane == 0) out[0] = (lz - gs) / ln;
  }
}

extern "C" void kernel_launch(void* const* d_in, const int* in_sizes, int n_in,
                              void* d_out, int out_size, void* d_ws, size_t ws_size,
                              hipStream_t stream) {
  const float* emits   = (const float*)d_in[0];
  const int*   targets = (const int*)d_in[1];
  const int*   mask    = (const int*)d_in[2];
  float* out = (float*)d_out;

  _Float16* matP = (_Float16*)d_ws;                                   // 8 MB
  float*    wsf  = (float*)((char*)d_ws + (size_t)NCHUNKS * 4096 * 2);
  float*    wso  = wsf + 2 * NCHUNKS;
  int*      done = (int*)(wso + 64);

  hipMemsetAsync(done, 0, sizeof(int), stream);
  hipLaunchKernelGGL(crf_chunk, dim3(NCHUNKS), dim3(64), 0, stream,
                     emits, targets, mask, matP, wsf);
  hipLaunchKernelGGL(crf_fold, dim3(NB), dim3(64), 0, stream,
                     emits, mask, matP, wsf, wso, done, out);
}